// Round 2
// baseline (1276.177 us; speedup 1.0000x reference)
//
#include <hip/hip_runtime.h>
#include <hip/hip_bf16.h>

#define MDIM 4096      // B*S tokens
#define DDIM 512
#define ADIM 64
#define HHEADS 8
#define SLEN 2048
#define TDIM 256

__device__ __forceinline__ void f4_to_arr(float4 v, float* a) {
    a[0] = v.x; a[1] = v.y; a[2] = v.z; a[3] = v.w;
}

// ---------------------------------------------------------------------------
// Generic fp32 GEMM: C[M,N] = A[M,K] @ B[K,N] + bias ; flags: 1=relu
// 64x64 tile, TK=16, 256 threads, 4x4 per-thread micro-tile. fp32 out.
// ---------------------------------------------------------------------------
__global__ __launch_bounds__(256) void gemm_k(
    const float* __restrict__ A, const float* __restrict__ Bm,
    const float* __restrict__ bias, float* __restrict__ Cf,
    int M, int N, int K, int flags)
{
    __shared__ float As[16][64];   // [k][m]
    __shared__ float Bs[16][64];   // [k][n]
    const int tid = threadIdx.x;
    const int tx = tid & 15, ty = tid >> 4;
    const int m0 = blockIdx.y * 64, n0 = blockIdx.x * 64;

    float acc[4][4];
#pragma unroll
    for (int i = 0; i < 4; ++i)
#pragma unroll
        for (int j = 0; j < 4; ++j) acc[i][j] = 0.f;

    const int ra = tid >> 2, kq = tid & 3;   // A-load mapping
    const int kb = tid >> 4, c4 = tid & 15;  // B-load mapping

    for (int k0 = 0; k0 < K; k0 += 16) {
        __syncthreads();
        float4 a4 = *(const float4*)&A[(size_t)(m0 + ra) * K + k0 + kq * 4];
        As[kq * 4 + 0][ra] = a4.x; As[kq * 4 + 1][ra] = a4.y;
        As[kq * 4 + 2][ra] = a4.z; As[kq * 4 + 3][ra] = a4.w;
        float4 b4 = *(const float4*)&Bm[(size_t)(k0 + kb) * N + n0 + c4 * 4];
        *(float4*)&Bs[kb][c4 * 4] = b4;
        __syncthreads();
#pragma unroll
        for (int kk = 0; kk < 16; ++kk) {
            float ar[4], br[4];
            f4_to_arr(*(const float4*)&As[kk][ty * 4], ar);
            f4_to_arr(*(const float4*)&Bs[kk][tx * 4], br);
#pragma unroll
            for (int i = 0; i < 4; ++i)
#pragma unroll
                for (int j = 0; j < 4; ++j)
                    acc[i][j] = fmaf(ar[i], br[j], acc[i][j]);
        }
    }

    float bb[4];
#pragma unroll
    for (int j = 0; j < 4; ++j) bb[j] = bias[n0 + tx * 4 + j];

#pragma unroll
    for (int i = 0; i < 4; ++i) {
        int row = m0 + ty * 4 + i;
        float vv[4];
#pragma unroll
        for (int j = 0; j < 4; ++j) {
            float v = acc[i][j] + bb[j];
            if (flags & 1) v = fmaxf(v, 0.f);
            vv[j] = v;
        }
        float4 o; o.x = vv[0]; o.y = vv[1]; o.z = vv[2]; o.w = vv[3];
        *(float4*)&Cf[(size_t)row * N + n0 + tx * 4] = o;
    }
}

// ---------------------------------------------------------------------------
// QKV: per-head GEMM  q[b,h,s,a] = x[b,s,:] @ Wq[h,:,:] + bq[h,a]
// grid: (M/64, H, 3) ; W layout [H, D, A] row-major per head (ldb = A)
// ---------------------------------------------------------------------------
__global__ __launch_bounds__(256) void qkv_k(
    const float* __restrict__ X,
    const float* __restrict__ Wq, const float* __restrict__ Wk, const float* __restrict__ Wv,
    const float* __restrict__ bq, const float* __restrict__ bk, const float* __restrict__ bv,
    float* __restrict__ Oq, float* __restrict__ Ok, float* __restrict__ Ov)
{
    __shared__ float As[16][64];
    __shared__ float Bs[16][64];
    const int tid = threadIdx.x;
    const int tx = tid & 15, ty = tid >> 4;
    const int m0 = blockIdx.x * 64;
    const int h = blockIdx.y;
    const int which = blockIdx.z;

    const float* W = (which == 0) ? Wq : (which == 1) ? Wk : Wv;
    const float* bptr = (which == 0) ? bq : (which == 1) ? bk : bv;
    float* Out = (which == 0) ? Oq : (which == 1) ? Ok : Ov;
    W += (size_t)h * DDIM * ADIM;
    bptr += h * ADIM;

    float acc[4][4];
#pragma unroll
    for (int i = 0; i < 4; ++i)
#pragma unroll
        for (int j = 0; j < 4; ++j) acc[i][j] = 0.f;

    const int ra = tid >> 2, kq = tid & 3;
    const int kb = tid >> 4, c4 = tid & 15;

    for (int k0 = 0; k0 < DDIM; k0 += 16) {
        __syncthreads();
        float4 a4 = *(const float4*)&X[(size_t)(m0 + ra) * DDIM + k0 + kq * 4];
        As[kq * 4 + 0][ra] = a4.x; As[kq * 4 + 1][ra] = a4.y;
        As[kq * 4 + 2][ra] = a4.z; As[kq * 4 + 3][ra] = a4.w;
        float4 b4 = *(const float4*)&W[(size_t)(k0 + kb) * ADIM + c4 * 4];
        *(float4*)&Bs[kb][c4 * 4] = b4;
        __syncthreads();
#pragma unroll
        for (int kk = 0; kk < 16; ++kk) {
            float ar[4], br[4];
            f4_to_arr(*(const float4*)&As[kk][ty * 4], ar);
            f4_to_arr(*(const float4*)&Bs[kk][tx * 4], br);
#pragma unroll
            for (int i = 0; i < 4; ++i)
#pragma unroll
                for (int j = 0; j < 4; ++j)
                    acc[i][j] = fmaf(ar[i], br[j], acc[i][j]);
        }
    }

    const int b = m0 >> 11;            // m0 / SLEN
    const int s0 = m0 & (SLEN - 1);
    float* Ob = Out + ((size_t)(b * HHEADS + h) * SLEN + s0) * ADIM;
    float bb[4];
#pragma unroll
    for (int j = 0; j < 4; ++j) bb[j] = bptr[tx * 4 + j];
#pragma unroll
    for (int i = 0; i < 4; ++i) {
        float vv[4];
#pragma unroll
        for (int j = 0; j < 4; ++j) vv[j] = acc[i][j] + bb[j];
        float4 o; o.x = vv[0]; o.y = vv[1]; o.z = vv[2]; o.w = vv[3];
        *(float4*)&Ob[(size_t)(ty * 4 + i) * ADIM + tx * 4] = o;
    }
}

// ---------------------------------------------------------------------------
// Flash attention (fp32): one block = 64 query rows of one (b,h).
// grid: (S/64, B*H), 256 threads. Online softmax; (m,l) replicated in
// registers across each row's 16-lane group (wave-uniform shuffles).
// Writes concat layout hcat[b,s,h*A+a].
// ---------------------------------------------------------------------------
__global__ __launch_bounds__(256) void attn_k(
    const float* __restrict__ Q, const float* __restrict__ K,
    const float* __restrict__ V, float* __restrict__ Hc)
{
    __shared__ float Qs[64][64];   // [row][d]
    __shared__ float Kt[64][64];   // [d][key]   (transposed)
    __shared__ float Vs[64][64];   // [key][d]
    __shared__ float Ps[64][64];   // [row][key]

    const int tid = threadIdx.x;
    const int tx = tid & 15, ty = tid >> 4;
    const int bh = blockIdx.y;
    const int s0 = blockIdx.x * 64;

    const float* Qb = Q + (size_t)bh * SLEN * ADIM;
    const float* Kb = K + (size_t)bh * SLEN * ADIM;
    const float* Vb = V + (size_t)bh * SLEN * ADIM;

    const int lr = tid >> 2, lq = tid & 3;
#pragma unroll
    for (int t = 0; t < 4; ++t) {
        int c = (lq + 4 * t) * 4;
        float4 q4 = *(const float4*)&Qb[(size_t)(s0 + lr) * ADIM + c];
        *(float4*)&Qs[lr][c] = q4;
    }

    float m_reg[4], l_reg[4], o_acc[4][4];
#pragma unroll
    for (int i = 0; i < 4; ++i) {
        m_reg[i] = -1e30f; l_reg[i] = 0.f;
#pragma unroll
        for (int j = 0; j < 4; ++j) o_acc[i][j] = 0.f;
    }

    for (int kt0 = 0; kt0 < SLEN; kt0 += 64) {
        __syncthreads();   // protect Kt/Vs/Ps from previous iteration's readers
#pragma unroll
        for (int t = 0; t < 4; ++t) {
            int c = (lq + 4 * t) * 4;
            float4 k4 = *(const float4*)&Kb[(size_t)(kt0 + lr) * ADIM + c];
            Kt[c + 0][lr] = k4.x; Kt[c + 1][lr] = k4.y;
            Kt[c + 2][lr] = k4.z; Kt[c + 3][lr] = k4.w;
            float4 v4 = *(const float4*)&Vb[(size_t)(kt0 + lr) * ADIM + c];
            *(float4*)&Vs[lr][c] = v4;
        }
        __syncthreads();

        // S = Q @ K^T  (rows ty*4+i, cols tx*4+j)
        float sacc[4][4];
#pragma unroll
        for (int i = 0; i < 4; ++i)
#pragma unroll
            for (int j = 0; j < 4; ++j) sacc[i][j] = 0.f;
#pragma unroll
        for (int d0 = 0; d0 < 64; d0 += 4) {
            float qr[4][4], kr[4][4];
#pragma unroll
            for (int i = 0; i < 4; ++i) f4_to_arr(*(const float4*)&Qs[ty * 4 + i][d0], qr[i]);
#pragma unroll
            for (int t = 0; t < 4; ++t) f4_to_arr(*(const float4*)&Kt[d0 + t][tx * 4], kr[t]);
#pragma unroll
            for (int i = 0; i < 4; ++i)
#pragma unroll
                for (int t = 0; t < 4; ++t)
#pragma unroll
                    for (int j = 0; j < 4; ++j)
                        sacc[i][j] = fmaf(qr[i][t], kr[t][j], sacc[i][j]);
        }

        // online softmax update per row
        float alpha[4];
#pragma unroll
        for (int i = 0; i < 4; ++i) {
            float rm = -1e30f;
#pragma unroll
            for (int j = 0; j < 4; ++j) { sacc[i][j] *= 0.125f; rm = fmaxf(rm, sacc[i][j]); }
#pragma unroll
            for (int off = 1; off < 16; off <<= 1) rm = fmaxf(rm, __shfl_xor(rm, off));
            float mnew = fmaxf(m_reg[i], rm);
            float ai = __expf(m_reg[i] - mnew);
            float rs = 0.f, pj[4];
#pragma unroll
            for (int j = 0; j < 4; ++j) { pj[j] = __expf(sacc[i][j] - mnew); rs += pj[j]; }
            float4 p4; p4.x = pj[0]; p4.y = pj[1]; p4.z = pj[2]; p4.w = pj[3];
            *(float4*)&Ps[ty * 4 + i][tx * 4] = p4;
#pragma unroll
            for (int off = 1; off < 16; off <<= 1) rs += __shfl_xor(rs, off);
            m_reg[i] = mnew;
            l_reg[i] = l_reg[i] * ai + rs;
            alpha[i] = ai;
        }
        __syncthreads();   // Ps fully written before PV

        // O = O*alpha + P @ V   (rows ty*4+i, d-cols tx*4+j)
#pragma unroll
        for (int i = 0; i < 4; ++i)
#pragma unroll
            for (int j = 0; j < 4; ++j) o_acc[i][j] *= alpha[i];
#pragma unroll
        for (int c0 = 0; c0 < 64; c0 += 4) {
            float pr[4][4], vr[4][4];
#pragma unroll
            for (int i = 0; i < 4; ++i) f4_to_arr(*(const float4*)&Ps[ty * 4 + i][c0], pr[i]);
#pragma unroll
            for (int t = 0; t < 4; ++t) f4_to_arr(*(const float4*)&Vs[c0 + t][tx * 4], vr[t]);
#pragma unroll
            for (int i = 0; i < 4; ++i)
#pragma unroll
                for (int t = 0; t < 4; ++t)
#pragma unroll
                    for (int j = 0; j < 4; ++j)
                        o_acc[i][j] = fmaf(pr[i][t], vr[t][j], o_acc[i][j]);
        }
    }

    const int b = bh >> 3, h = bh & 7;
#pragma unroll
    for (int i = 0; i < 4; ++i) {
        int r = ty * 4 + i;
        float inv = 1.f / l_reg[i];
        float4 o4;
        o4.x = o_acc[i][0] * inv; o4.y = o_acc[i][1] * inv;
        o4.z = o_acc[i][2] * inv; o4.w = o_acc[i][3] * inv;
        *(float4*)&Hc[(size_t)((b * SLEN + s0 + r) * HHEADS + h) * ADIM + tx * 4] = o4;
    }
}

// ---------------------------------------------------------------------------
// AddNorm: x = LN(x + y) * g + b   ; one wave per token, 4 tokens/block
// ---------------------------------------------------------------------------
__global__ __launch_bounds__(256) void addnorm_k(
    float* __restrict__ X, const float* __restrict__ Y,
    const float* __restrict__ g, const float* __restrict__ beta)
{
    const int lane = threadIdx.x & 63;
    const int t = blockIdx.x * 4 + (threadIdx.x >> 6);
    float* xr = X + (size_t)t * DDIM;
    const float* yr = Y + (size_t)t * DDIM;
    const int c0 = lane * 4, c1 = 256 + lane * 4;

    float4 x0 = *(const float4*)&xr[c0]; float4 y0 = *(const float4*)&yr[c0];
    float4 x1 = *(const float4*)&xr[c1]; float4 y1 = *(const float4*)&yr[c1];
    float v0[4] = {x0.x + y0.x, x0.y + y0.y, x0.z + y0.z, x0.w + y0.w};
    float v1[4] = {x1.x + y1.x, x1.y + y1.y, x1.z + y1.z, x1.w + y1.w};

    float s1 = 0.f, s2 = 0.f;
#pragma unroll
    for (int j = 0; j < 4; ++j) { s1 += v0[j] + v1[j]; s2 += v0[j] * v0[j] + v1[j] * v1[j]; }
#pragma unroll
    for (int off = 1; off < 64; off <<= 1) {
        s1 += __shfl_xor(s1, off);
        s2 += __shfl_xor(s2, off);
    }
    float mean = s1 * (1.0f / DDIM);
    float var = s2 * (1.0f / DDIM) - mean * mean;
    float rstd = rsqrtf(var + 1e-5f);

    float4 g0 = *(const float4*)&g[c0]; float4 b0 = *(const float4*)&beta[c0];
    float4 g1_ = *(const float4*)&g[c1]; float4 b1_ = *(const float4*)&beta[c1];
    float ga0[4], ba0[4], ga1[4], ba1[4];
    f4_to_arr(g0, ga0); f4_to_arr(b0, ba0); f4_to_arr(g1_, ga1); f4_to_arr(b1_, ba1);

    float o0[4], o1[4];
#pragma unroll
    for (int j = 0; j < 4; ++j) {
        o0[j] = (v0[j] - mean) * rstd * ga0[j] + ba0[j];
        o1[j] = (v1[j] - mean) * rstd * ga1[j] + ba1[j];
    }
    float4 w0; w0.x = o0[0]; w0.y = o0[1]; w0.z = o0[2]; w0.w = o0[3];
    float4 w1; w1.x = o1[0]; w1.y = o1[1]; w1.z = o1[2]; w1.w = o1[3];
    *(float4*)&xr[c0] = w0;
    *(float4*)&xr[c1] = w1;
}

// ---------------------------------------------------------------------------
extern "C" void kernel_launch(void* const* d_in, const int* in_sizes, int n_in,
                              void* d_out, int out_size, void* d_ws, size_t ws_size,
                              hipStream_t stream)
{
    (void)in_sizes; (void)n_in; (void)out_size; (void)ws_size;
    const float* x   = (const float*)d_in[0];
    const float* Wq  = (const float*)d_in[1];
    const float* bq  = (const float*)d_in[2];
    const float* Wk  = (const float*)d_in[3];
    const float* bk  = (const float*)d_in[4];
    const float* Wv  = (const float*)d_in[5];
    const float* bv  = (const float*)d_in[6];
    const float* Wo  = (const float*)d_in[7];
    const float* bo  = (const float*)d_in[8];
    const float* g1  = (const float*)d_in[9];
    const float* be1 = (const float*)d_in[10];
    const float* W1  = (const float*)d_in[11];
    const float* b1  = (const float*)d_in[12];
    const float* W2  = (const float*)d_in[13];
    const float* b2  = (const float*)d_in[14];
    const float* g2  = (const float*)d_in[15];
    const float* be2 = (const float*)d_in[16];
    const float* Wp  = (const float*)d_in[17];
    const float* bp  = (const float*)d_in[18];

    const size_t MD = (size_t)MDIM * DDIM;
    float* ws = (float*)d_ws;
    float* xw = ws;            // current activations [4096,512]
    float* qb = ws + MD;       // q  [B,H,S,A]   (reused: Wo-gemm out)
    float* kb = ws + 2 * MD;   // k              (reused: ffn hidden)
    float* vb = ws + 3 * MD;   // v              (reused: ffn2 out)
    float* hc = ws + 4 * MD;   // concat heads [4096, 512]

    hipMemcpyAsync(xw, x, MD * sizeof(float), hipMemcpyDeviceToDevice, stream);

    for (int i = 0; i < 2; ++i) {
        const size_t wOff = (size_t)i * HHEADS * DDIM * ADIM;
        qkv_k<<<dim3(64, 8, 3), 256, 0, stream>>>(
            xw, Wq + wOff, Wk + wOff, Wv + wOff,
            bq + i * HHEADS * ADIM, bk + i * HHEADS * ADIM, bv + i * HHEADS * ADIM,
            qb, kb, vb);
        attn_k<<<dim3(32, 16), 256, 0, stream>>>(qb, kb, vb, hc);
        gemm_k<<<dim3(8, 64), 256, 0, stream>>>(
            hc, Wo + (size_t)i * DDIM * DDIM, bo + i * DDIM, qb, MDIM, DDIM, DDIM, 0);
        addnorm_k<<<dim3(1024), 256, 0, stream>>>(xw, qb, g1 + i * DDIM, be1 + i * DDIM);
        gemm_k<<<dim3(8, 64), 256, 0, stream>>>(
            xw, W1 + (size_t)i * DDIM * DDIM, b1 + i * DDIM, kb, MDIM, DDIM, DDIM, 1);
        gemm_k<<<dim3(8, 64), 256, 0, stream>>>(
            kb, W2 + (size_t)i * DDIM * DDIM, b2 + i * DDIM, vb, MDIM, DDIM, DDIM, 0);
        addnorm_k<<<dim3(1024), 256, 0, stream>>>(xw, vb, g2 + i * DDIM, be2 + i * DDIM);
    }
    gemm_k<<<dim3(4, 64), 256, 0, stream>>>(
        xw, Wp, bp, (float*)d_out, MDIM, TDIM, DDIM, 0);
}

// Round 4
// 662.017 us; speedup vs baseline: 1.9277x; 1.9277x over previous
//
#include <hip/hip_runtime.h>
#include <hip/hip_bf16.h>

#define MDIM 4096      // B*S tokens
#define DDIM 512
#define ADIM 64
#define HHEADS 8
#define SLEN 2048
#define TDIM 256

typedef __attribute__((ext_vector_type(8))) short short8;
typedef __attribute__((ext_vector_type(16))) float f32x16;

__device__ __forceinline__ void f4_to_arr(float4 v, float* a) {
    a[0] = v.x; a[1] = v.y; a[2] = v.z; a[3] = v.w;
}

__device__ __forceinline__ unsigned short f2bf(float f) {
    union { __hip_bfloat16 h; unsigned short u; } c;
    c.h = __float2bfloat16(f);
    return c.u;
}

__device__ __forceinline__ int f2bf_pk(float a, float b) {
    return (int)((unsigned)f2bf(a) | ((unsigned)f2bf(b) << 16));
}

// ---------------------------------------------------------------------------
// Generic fp32 GEMM: C[M,N] = A[M,K] @ B[K,N] + bias ; flags: 1=relu
// ---------------------------------------------------------------------------
__global__ __launch_bounds__(256) void gemm_k(
    const float* __restrict__ A, const float* __restrict__ Bm,
    const float* __restrict__ bias, float* __restrict__ Cf,
    int M, int N, int K, int flags)
{
    __shared__ float As[16][64];
    __shared__ float Bs[16][64];
    const int tid = threadIdx.x;
    const int tx = tid & 15, ty = tid >> 4;
    const int m0 = blockIdx.y * 64, n0 = blockIdx.x * 64;

    float acc[4][4];
#pragma unroll
    for (int i = 0; i < 4; ++i)
#pragma unroll
        for (int j = 0; j < 4; ++j) acc[i][j] = 0.f;

    const int ra = tid >> 2, kq = tid & 3;
    const int kb = tid >> 4, c4 = tid & 15;

    for (int k0 = 0; k0 < K; k0 += 16) {
        __syncthreads();
        float4 a4 = *(const float4*)&A[(size_t)(m0 + ra) * K + k0 + kq * 4];
        As[kq * 4 + 0][ra] = a4.x; As[kq * 4 + 1][ra] = a4.y;
        As[kq * 4 + 2][ra] = a4.z; As[kq * 4 + 3][ra] = a4.w;
        float4 b4 = *(const float4*)&Bm[(size_t)(k0 + kb) * N + n0 + c4 * 4];
        *(float4*)&Bs[kb][c4 * 4] = b4;
        __syncthreads();
#pragma unroll
        for (int kk = 0; kk < 16; ++kk) {
            float ar[4], br[4];
            f4_to_arr(*(const float4*)&As[kk][ty * 4], ar);
            f4_to_arr(*(const float4*)&Bs[kk][tx * 4], br);
#pragma unroll
            for (int i = 0; i < 4; ++i)
#pragma unroll
                for (int j = 0; j < 4; ++j)
                    acc[i][j] = fmaf(ar[i], br[j], acc[i][j]);
        }
    }

    float bb[4];
#pragma unroll
    for (int j = 0; j < 4; ++j) bb[j] = bias[n0 + tx * 4 + j];

#pragma unroll
    for (int i = 0; i < 4; ++i) {
        int row = m0 + ty * 4 + i;
        float vv[4];
#pragma unroll
        for (int j = 0; j < 4; ++j) {
            float v = acc[i][j] + bb[j];
            if (flags & 1) v = fmaxf(v, 0.f);
            vv[j] = v;
        }
        float4 o; o.x = vv[0]; o.y = vv[1]; o.z = vv[2]; o.w = vv[3];
        *(float4*)&Cf[(size_t)row * N + n0 + tx * 4] = o;
    }
}

// ---------------------------------------------------------------------------
// QKV per-head GEMM (fp32 compute), bf16 outputs.
// Q,K -> [bh][s][64] bf16 ; V -> TRANSPOSED [bh][d=64][s] bf16.
// ---------------------------------------------------------------------------
__global__ __launch_bounds__(256) void qkv_k(
    const float* __restrict__ X,
    const float* __restrict__ Wq, const float* __restrict__ Wk, const float* __restrict__ Wv,
    const float* __restrict__ bq, const float* __restrict__ bk, const float* __restrict__ bv,
    short* __restrict__ Oq, short* __restrict__ Ok, short* __restrict__ Ov)
{
    __shared__ float As[16][64];
    __shared__ float Bs[16][64];
    const int tid = threadIdx.x;
    const int tx = tid & 15, ty = tid >> 4;
    const int m0 = blockIdx.x * 64;
    const int h = blockIdx.y;
    const int which = blockIdx.z;

    const float* W = (which == 0) ? Wq : (which == 1) ? Wk : Wv;
    const float* bptr = (which == 0) ? bq : (which == 1) ? bk : bv;
    short* Out = (which == 0) ? Oq : (which == 1) ? Ok : Ov;
    W += (size_t)h * DDIM * ADIM;
    bptr += h * ADIM;

    float acc[4][4];
#pragma unroll
    for (int i = 0; i < 4; ++i)
#pragma unroll
        for (int j = 0; j < 4; ++j) acc[i][j] = 0.f;

    const int ra = tid >> 2, kq = tid & 3;
    const int kb = tid >> 4, c4 = tid & 15;

    for (int k0 = 0; k0 < DDIM; k0 += 16) {
        __syncthreads();
        float4 a4 = *(const float4*)&X[(size_t)(m0 + ra) * DDIM + k0 + kq * 4];
        As[kq * 4 + 0][ra] = a4.x; As[kq * 4 + 1][ra] = a4.y;
        As[kq * 4 + 2][ra] = a4.z; As[kq * 4 + 3][ra] = a4.w;
        float4 b4 = *(const float4*)&W[(size_t)(k0 + kb) * ADIM + c4 * 4];
        *(float4*)&Bs[kb][c4 * 4] = b4;
        __syncthreads();
#pragma unroll
        for (int kk = 0; kk < 16; ++kk) {
            float ar[4], br[4];
            f4_to_arr(*(const float4*)&As[kk][ty * 4], ar);
            f4_to_arr(*(const float4*)&Bs[kk][tx * 4], br);
#pragma unroll
            for (int i = 0; i < 4; ++i)
#pragma unroll
                for (int j = 0; j < 4; ++j)
                    acc[i][j] = fmaf(ar[i], br[j], acc[i][j]);
        }
    }

    const int b = m0 >> 11;
    const int s0 = m0 & (SLEN - 1);
    const int bh = b * HHEADS + h;
    float bb[4];
#pragma unroll
    for (int j = 0; j < 4; ++j) bb[j] = bptr[tx * 4 + j];

    if (which < 2) {
        short* Ob = Out + ((size_t)bh * SLEN + s0) * 64;
#pragma unroll
        for (int i = 0; i < 4; ++i) {
            ushort4 w;
            w.x = f2bf(acc[i][0] + bb[0]);
            w.y = f2bf(acc[i][1] + bb[1]);
            w.z = f2bf(acc[i][2] + bb[2]);
            w.w = f2bf(acc[i][3] + bb[3]);
            *(ushort4*)&Ob[(size_t)(ty * 4 + i) * 64 + tx * 4] = w;
        }
    } else {
        // V transposed: Vt[bh][d][s]
        short* Ob = Out + (size_t)bh * 64 * SLEN;
#pragma unroll
        for (int j = 0; j < 4; ++j) {
            ushort4 w;
            w.x = f2bf(acc[0][j] + bb[j]);
            w.y = f2bf(acc[1][j] + bb[j]);
            w.z = f2bf(acc[2][j] + bb[j]);
            w.w = f2bf(acc[3][j] + bb[j]);
            *(ushort4*)&Ob[(size_t)(tx * 4 + j) * SLEN + s0 + ty * 4] = w;
        }
    }
}

// ---------------------------------------------------------------------------
// MFMA flash attention, no-max softmax, key-split.
// grid (qt=8, bh=16, split=4), 256 threads = 4 waves; wave owns 64 q-rows.
// S^T = K·Q^T via mfma_32x32x16_bf16; PV a-frags built in-register.
// ---------------------------------------------------------------------------
#define EXPC 0.1803368801111244f   // 0.125 * log2(e)

__global__ __launch_bounds__(256, 2) void attn_mfma(
    const short* __restrict__ Qb, const short* __restrict__ Kb,
    const short* __restrict__ Vtb, short* __restrict__ Op,
    float* __restrict__ lp)
{
    __shared__ short Ks[64 * 72];   // [key][d], row stride 72 (pad)
    __shared__ short Vs[64 * 72];   // [d][key], row stride 72

    const int tid = threadIdx.x;
    const int wid = tid >> 6;
    const int lane = tid & 63;
    const int l31 = lane & 31;
    const int hi = lane >> 5;

    const int qt = blockIdx.x;
    const int bh = blockIdx.y;
    const int sp = blockIdx.z;

    const short* Qg = Qb + (size_t)bh * SLEN * 64;
    const short* Kg = Kb + (size_t)bh * SLEN * 64;
    const short* Vg = Vtb + (size_t)bh * 64 * SLEN;

    const int q0 = qt * 256 + wid * 64;

    // preload Q fragments (constant across key tiles)
    short8 qf[2][4];
#pragma unroll
    for (int nt = 0; nt < 2; ++nt)
#pragma unroll
        for (int ks = 0; ks < 4; ++ks)
            qf[nt][ks] = *(const short8*)&Qg[(size_t)(q0 + nt * 32 + l31) * 64 + ks * 16 + hi * 8];

    f32x16 oacc[2][2];
#pragma unroll
    for (int nt = 0; nt < 2; ++nt)
#pragma unroll
        for (int dt = 0; dt < 2; ++dt)
#pragma unroll
            for (int r = 0; r < 16; ++r) oacc[nt][dt][r] = 0.f;
    float lsum[2] = {0.f, 0.f};

    const int srow = tid >> 2;          // staging: row 0..63
    const int sch = (tid & 3) * 16;     // staging: 16-elem chunk (full 64-wide rows)

    for (int kt = 0; kt < 8; ++kt) {
        const int k0 = sp * 512 + kt * 64;
        __syncthreads();
        *(short8*)&Ks[srow * 72 + sch]     = *(const short8*)&Kg[(size_t)(k0 + srow) * 64 + sch];
        *(short8*)&Ks[srow * 72 + sch + 8] = *(const short8*)&Kg[(size_t)(k0 + srow) * 64 + sch + 8];
        *(short8*)&Vs[srow * 72 + sch]     = *(const short8*)&Vg[(size_t)srow * SLEN + k0 + sch];
        *(short8*)&Vs[srow * 72 + sch + 8] = *(const short8*)&Vg[(size_t)srow * SLEN + k0 + sch + 8];
        __syncthreads();

        short8 kf[2][4], vf[2][4];
#pragma unroll
        for (int mt = 0; mt < 2; ++mt)
#pragma unroll
            for (int ks = 0; ks < 4; ++ks)
                kf[mt][ks] = *(const short8*)&Ks[(mt * 32 + l31) * 72 + ks * 16 + hi * 8];
#pragma unroll
        for (int dt = 0; dt < 2; ++dt)
#pragma unroll
            for (int p = 0; p < 4; ++p)
                vf[dt][p] = *(const short8*)&Vs[(dt * 32 + l31) * 72 + p * 16 + hi * 8];

#pragma unroll
        for (int nt = 0; nt < 2; ++nt) {
            // S^T tiles: sacc[mt] rows = keys mt*32..+31, col = q = nt*32+l31
            f32x16 sacc[2];
#pragma unroll
            for (int mt = 0; mt < 2; ++mt) {
                f32x16 s;
#pragma unroll
                for (int r = 0; r < 16; ++r) s[r] = 0.f;
#pragma unroll
                for (int ks = 0; ks < 4; ++ks)
                    s = __builtin_amdgcn_mfma_f32_32x32x16_bf16(kf[mt][ks], qf[nt][ks], s, 0, 0, 0);
                sacc[mt] = s;
            }

            // softmax (no max-sub): p = exp2(s*EXPC); pack to bf16 pairs
            int2 pk[2][4], sh[2][4];
#pragma unroll
            for (int mt = 0; mt < 2; ++mt) {
#pragma unroll
                for (int g = 0; g < 4; ++g) {
                    float p0 = exp2f(sacc[mt][4 * g + 0] * EXPC);
                    float p1 = exp2f(sacc[mt][4 * g + 1] * EXPC);
                    float p2 = exp2f(sacc[mt][4 * g + 2] * EXPC);
                    float p3 = exp2f(sacc[mt][4 * g + 3] * EXPC);
                    lsum[nt] += (p0 + p1) + (p2 + p3);
                    pk[mt][g].x = f2bf_pk(p0, p1);
                    pk[mt][g].y = f2bf_pk(p2, p3);
                    sh[mt][g].x = __shfl_xor(pk[mt][g].x, 32);
                    sh[mt][g].y = __shfl_xor(pk[mt][g].y, 32);
                }
            }

            // PV: O[q][d] += P[q][key] * V[key][d], 4 k-steps of 16 keys
#pragma unroll
            for (int p = 0; p < 4; ++p) {
                const int mt = p >> 1, h2 = p & 1;
                const int ga = 2 * h2, gb = 2 * h2 + 1;
                union { int4 i; short8 s; } u;
                u.i.x = hi ? sh[mt][gb].x : pk[mt][ga].x;
                u.i.y = hi ? sh[mt][gb].y : pk[mt][ga].y;
                u.i.z = hi ? pk[mt][gb].x : sh[mt][ga].x;
                u.i.w = hi ? pk[mt][gb].y : sh[mt][ga].y;
#pragma unroll
                for (int dt = 0; dt < 2; ++dt)
                    oacc[nt][dt] = __builtin_amdgcn_mfma_f32_32x32x16_bf16(u.s, vf[dt][p], oacc[nt][dt], 0, 0, 0);
            }
        }
    }

    // epilogue: partial l and unnormalized partial O (bf16)
#pragma unroll
    for (int nt = 0; nt < 2; ++nt) {
        float lt = lsum[nt] + __shfl_xor(lsum[nt], 32);
        if (hi == 0)
            lp[((size_t)(sp * 16 + bh)) * SLEN + q0 + nt * 32 + l31] = lt;
#pragma unroll
        for (int dt = 0; dt < 2; ++dt) {
#pragma unroll
            for (int r = 0; r < 16; ++r) {
                int qrow = (r & 3) + 8 * (r >> 2) + 4 * hi;
                size_t addr = (((size_t)(sp * 16 + bh)) * SLEN + (q0 + nt * 32 + qrow)) * 64 + dt * 32 + l31;
                Op[addr] = (short)f2bf(oacc[nt][dt][r]);
            }
        }
    }
}

// ---------------------------------------------------------------------------
// Merge key-split partials: hc[b,s, h*64+d] = sum_sp O / sum_sp l
// ---------------------------------------------------------------------------
__global__ __launch_bounds__(256) void merge_k(
    const short* __restrict__ Op, const float* __restrict__ lp,
    float* __restrict__ hc)
{
    const int g = blockIdx.x * 256 + threadIdx.x;
    const int d = g & 63;
    const int s = (g >> 6) & (SLEN - 1);
    const int bh = g >> 17;

    float o = 0.f, ls = 0.f;
#pragma unroll
    for (int sp = 0; sp < 4; ++sp) {
        unsigned short ub = (unsigned short)Op[(((size_t)(sp * 16 + bh)) * SLEN + s) * 64 + d];
        o += __uint_as_float((unsigned)ub << 16);
        ls += lp[((size_t)(sp * 16 + bh)) * SLEN + s];
    }
    const int b = bh >> 3, h = bh & 7;
    hc[((size_t)(b * SLEN + s)) * DDIM + h * 64 + d] = o / ls;
}

// ---------------------------------------------------------------------------
// AddNorm: x = LN(x + y) * g + b
// ---------------------------------------------------------------------------
__global__ __launch_bounds__(256) void addnorm_k(
    float* __restrict__ X, const float* __restrict__ Y,
    const float* __restrict__ g, const float* __restrict__ beta)
{
    const int lane = threadIdx.x & 63;
    const int t = blockIdx.x * 4 + (threadIdx.x >> 6);
    float* xr = X + (size_t)t * DDIM;
    const float* yr = Y + (size_t)t * DDIM;
    const int c0 = lane * 4, c1 = 256 + lane * 4;

    float4 x0 = *(const float4*)&xr[c0]; float4 y0 = *(const float4*)&yr[c0];
    float4 x1 = *(const float4*)&xr[c1]; float4 y1 = *(const float4*)&yr[c1];
    float v0[4] = {x0.x + y0.x, x0.y + y0.y, x0.z + y0.z, x0.w + y0.w};
    float v1[4] = {x1.x + y1.x, x1.y + y1.y, x1.z + y1.z, x1.w + y1.w};

    float s1 = 0.f, s2 = 0.f;
#pragma unroll
    for (int j = 0; j < 4; ++j) { s1 += v0[j] + v1[j]; s2 += v0[j] * v0[j] + v1[j] * v1[j]; }
#pragma unroll
    for (int off = 1; off < 64; off <<= 1) {
        s1 += __shfl_xor(s1, off);
        s2 += __shfl_xor(s2, off);
    }
    float mean = s1 * (1.0f / DDIM);
    float var = s2 * (1.0f / DDIM) - mean * mean;
    float rstd = rsqrtf(var + 1e-5f);

    float4 g0 = *(const float4*)&g[c0]; float4 b0 = *(const float4*)&beta[c0];
    float4 g1_ = *(const float4*)&g[c1]; float4 b1_ = *(const float4*)&beta[c1];
    float ga0[4], ba0[4], ga1[4], ba1[4];
    f4_to_arr(g0, ga0); f4_to_arr(b0, ba0); f4_to_arr(g1_, ga1); f4_to_arr(b1_, ba1);

    float o0[4], o1[4];
#pragma unroll
    for (int j = 0; j < 4; ++j) {
        o0[j] = (v0[j] - mean) * rstd * ga0[j] + ba0[j];
        o1[j] = (v1[j] - mean) * rstd * ga1[j] + ba1[j];
    }
    float4 w0; w0.x = o0[0]; w0.y = o0[1]; w0.z = o0[2]; w0.w = o0[3];
    float4 w1; w1.x = o1[0]; w1.y = o1[1]; w1.z = o1[2]; w1.w = o1[3];
    *(float4*)&xr[c0] = w0;
    *(float4*)&xr[c1] = w1;
}

// ---------------------------------------------------------------------------
// Workspace map (MiB), lifetime-checked overlays, total 36.5 MiB:
//   [ 0, 8)  xw        (alive whole run)
//   [ 8,12)  Qbuf      | hc [8,16) overlays Q/K: hc written at merge, Q/K dead
//   [12,16)  Kbuf      |
//   [16,20)  Vtbuf     | y [16,24): written at Wo-gemm, Vt+Opart head dead
//   [20,36)  Opart     | hid [24,32) overlays Opart mid: written at ffn1, dead
//   [36,36.5) lpart
// ---------------------------------------------------------------------------
extern "C" void kernel_launch(void* const* d_in, const int* in_sizes, int n_in,
                              void* d_out, int out_size, void* d_ws, size_t ws_size,
                              hipStream_t stream)
{
    (void)in_sizes; (void)n_in; (void)out_size; (void)ws_size;
    const float* x   = (const float*)d_in[0];
    const float* Wq  = (const float*)d_in[1];
    const float* bq  = (const float*)d_in[2];
    const float* Wk  = (const float*)d_in[3];
    const float* bk  = (const float*)d_in[4];
    const float* Wv  = (const float*)d_in[5];
    const float* bv  = (const float*)d_in[6];
    const float* Wo  = (const float*)d_in[7];
    const float* bo  = (const float*)d_in[8];
    const float* g1  = (const float*)d_in[9];
    const float* be1 = (const float*)d_in[10];
    const float* W1  = (const float*)d_in[11];
    const float* b1  = (const float*)d_in[12];
    const float* W2  = (const float*)d_in[13];
    const float* b2  = (const float*)d_in[14];
    const float* g2  = (const float*)d_in[15];
    const float* be2 = (const float*)d_in[16];
    const float* Wp  = (const float*)d_in[17];
    const float* bp  = (const float*)d_in[18];

    char* wsb = (char*)d_ws;
    const size_t MB = 1024 * 1024;
    float* xw    = (float*)(wsb + 0);
    short* Qbuf  = (short*)(wsb + 8 * MB);
    short* Kbuf  = (short*)(wsb + 12 * MB);
    short* Vtbuf = (short*)(wsb + 16 * MB);
    short* Opart = (short*)(wsb + 20 * MB);
    float* lpart = (float*)(wsb + 36 * MB);
    float* hc    = (float*)(wsb + 8 * MB);    // overlays Q/K (dead at merge)
    float* y     = (float*)(wsb + 16 * MB);   // overlays Vt + Opart[0:4M) (dead at Wo-gemm)
    float* hid   = (float*)(wsb + 24 * MB);   // overlays Opart[4:12M) (dead at ffn1)

    const size_t MD = (size_t)MDIM * DDIM;
    hipMemcpyAsync(xw, x, MD * sizeof(float), hipMemcpyDeviceToDevice, stream);

    for (int i = 0; i < 2; ++i) {
        const size_t wOff = (size_t)i * HHEADS * DDIM * ADIM;
        qkv_k<<<dim3(64, 8, 3), 256, 0, stream>>>(
            xw, Wq + wOff, Wk + wOff, Wv + wOff,
            bq + i * HHEADS * ADIM, bk + i * HHEADS * ADIM, bv + i * HHEADS * ADIM,
            Qbuf, Kbuf, Vtbuf);
        attn_mfma<<<dim3(8, 16, 4), 256, 0, stream>>>(Qbuf, Kbuf, Vtbuf, Opart, lpart);
        merge_k<<<8192, 256, 0, stream>>>(Opart, lpart, hc);
        gemm_k<<<dim3(8, 64), 256, 0, stream>>>(
            hc, Wo + (size_t)i * DDIM * DDIM, bo + i * DDIM, y, MDIM, DDIM, DDIM, 0);
        addnorm_k<<<dim3(1024), 256, 0, stream>>>(xw, y, g1 + i * DDIM, be1 + i * DDIM);
        gemm_k<<<dim3(8, 64), 256, 0, stream>>>(
            xw, W1 + (size_t)i * DDIM * DDIM, b1 + i * DDIM, hid, MDIM, DDIM, DDIM, 1);
        gemm_k<<<dim3(8, 64), 256, 0, stream>>>(
            hid, W2 + (size_t)i * DDIM * DDIM, b2 + i * DDIM, y, MDIM, DDIM, DDIM, 0);
        addnorm_k<<<dim3(1024), 256, 0, stream>>>(xw, y, g2 + i * DDIM, be2 + i * DDIM);
    }
    gemm_k<<<dim3(4, 64), 256, 0, stream>>>(
        xw, Wp, bp, (float*)d_out, MDIM, TDIM, DDIM, 0);
}

// Round 5
// 416.270 us; speedup vs baseline: 3.0657x; 1.5904x over previous
//
#include <hip/hip_runtime.h>
#include <hip/hip_bf16.h>

#define MDIM 4096      // B*S tokens
#define DDIM 512
#define ADIM 64
#define HHEADS 8
#define SLEN 2048
#define TDIM 256
#define SPLIT 2

typedef __attribute__((ext_vector_type(8))) short short8;
typedef __attribute__((ext_vector_type(16))) float f32x16;

__device__ __forceinline__ unsigned short f2bf(float f) {
    union { __hip_bfloat16 h; unsigned short u; } c;
    c.h = __float2bfloat16(f);
    return c.u;
}
__device__ __forceinline__ float bf2f(short s) {
    return __uint_as_float((unsigned)(unsigned short)s << 16);
}
__device__ __forceinline__ int f2bf_pk(float a, float b) {
    return (int)((unsigned)f2bf(a) | ((unsigned)f2bf(b) << 16));
}

// ---------------------------------------------------------------------------
// prep: weights fp32 -> bf16 transposed [n][k]; x -> bf16. One flat kernel.
//   Wq/Wk/Wv [L,H,D,A] -> [L,H,A,D] ; Wo/W1/W2 [L,K,N] -> [L,N,K] ;
//   Wp [K,N] -> [N,K] ; x fp32 -> bf16
// ---------------------------------------------------------------------------
#define N1 524288          // per qkv tensor out elems (16*64*512)
#define N2 524288          // per square weight
#define NP 131072
#define NX 2097152
__global__ __launch_bounds__(256) void prep_k(
    const float* __restrict__ Wq, const float* __restrict__ Wk, const float* __restrict__ Wv,
    const float* __restrict__ Wo, const float* __restrict__ W1, const float* __restrict__ W2,
    const float* __restrict__ Wp, const float* __restrict__ x,
    short* __restrict__ Wqt, short* __restrict__ Wkt, short* __restrict__ Wvt,
    short* __restrict__ Wot, short* __restrict__ W1t, short* __restrict__ W2t,
    short* __restrict__ Wpt, short* __restrict__ xbf)
{
    long idx = (long)blockIdx.x * 256 + threadIdx.x;
    if (idx < 3L * N1) {
        int t = (int)(idx / N1);
        int r = (int)(idx % N1);
        int k = r & 511, a = (r >> 9) & 63, hh = r >> 15;   // hh = i*8+h
        const float* src = (t == 0) ? Wq : (t == 1) ? Wk : Wv;
        short* dst = (t == 0) ? Wqt : (t == 1) ? Wkt : Wvt;
        dst[r] = (short)f2bf(src[((size_t)hh * 512 + k) * 64 + a]);
        return;
    }
    idx -= 3L * N1;
    if (idx < 3L * N2) {
        int t = (int)(idx / N2);
        int r = (int)(idx % N2);
        int k = r & 511, n = (r >> 9) & 511, i = r >> 18;
        const float* src = (t == 0) ? Wo : (t == 1) ? W1 : W2;
        short* dst = (t == 0) ? Wot : (t == 1) ? W1t : W2t;
        dst[r] = (short)f2bf(src[((size_t)i * 512 + k) * 512 + n]);
        return;
    }
    idx -= 3L * N2;
    if (idx < NP) {
        int r = (int)idx;
        int k = r & 511, n = r >> 9;
        Wpt[r] = (short)f2bf(Wp[(size_t)k * 256 + n]);
        return;
    }
    idx -= NP;
    xbf[idx] = (short)f2bf(x[idx]);
}

// ---------------------------------------------------------------------------
// bf16 MFMA GEMM: C[M,N] = A[M,K] @ B + bias. B given TRANSPOSED: Bt[n][k].
// Tile 128m x 64n, BK=64, 4 waves (2m x 2n), wave = 64m x 32n.
// flags: 1=relu, 2=bf16 out (else fp32).
// ---------------------------------------------------------------------------
#define LDT 66
__global__ __launch_bounds__(256, 2) void gemm_bf(
    const short* __restrict__ A, const short* __restrict__ Bt,
    const float* __restrict__ bias, void* __restrict__ Cout,
    int M, int N, int K, int flags)
{
    __shared__ short As[128 * LDT];
    __shared__ short Bs[64 * LDT];
    const int tid = threadIdx.x;
    const int wave = tid >> 6, lane = tid & 63;
    const int l31 = lane & 31, hi = lane >> 5;
    const int wm = wave >> 1, wn = wave & 1;
    const int m0 = blockIdx.y * 128, n0 = blockIdx.x * 64;

    f32x16 acc[2];
#pragma unroll
    for (int ms = 0; ms < 2; ++ms)
#pragma unroll
        for (int r = 0; r < 16; ++r) acc[ms][r] = 0.f;

    const int sr = tid >> 3;          // 0..31
    const int sc = (tid & 7) * 8;     // short chunk

    for (int k0 = 0; k0 < K; k0 += 64) {
        __syncthreads();
#pragma unroll
        for (int p = 0; p < 4; ++p)
            *(short8*)&As[(p * 32 + sr) * LDT + sc] =
                *(const short8*)&A[(size_t)(m0 + p * 32 + sr) * K + k0 + sc];
#pragma unroll
        for (int p = 0; p < 2; ++p)
            *(short8*)&Bs[(p * 32 + sr) * LDT + sc] =
                *(const short8*)&Bt[(size_t)(n0 + p * 32 + sr) * K + k0 + sc];
        __syncthreads();

        short8 af[2][4], bfm[4];
#pragma unroll
        for (int ms = 0; ms < 2; ++ms)
#pragma unroll
            for (int ks = 0; ks < 4; ++ks)
                af[ms][ks] = *(const short8*)&As[(wm * 64 + ms * 32 + l31) * LDT + ks * 16 + hi * 8];
#pragma unroll
        for (int ks = 0; ks < 4; ++ks)
            bfm[ks] = *(const short8*)&Bs[(wn * 32 + l31) * LDT + ks * 16 + hi * 8];
#pragma unroll
        for (int ms = 0; ms < 2; ++ms)
#pragma unroll
            for (int ks = 0; ks < 4; ++ks)
                acc[ms] = __builtin_amdgcn_mfma_f32_32x32x16_bf16(af[ms][ks], bfm[ks], acc[ms], 0, 0, 0);
    }

    const int col = n0 + wn * 32 + l31;
    const float bb = bias[col];
#pragma unroll
    for (int ms = 0; ms < 2; ++ms) {
        const int rbase = m0 + wm * 64 + ms * 32 + 4 * hi;
#pragma unroll
        for (int r = 0; r < 16; ++r) {
            int row = rbase + (r & 3) + 8 * (r >> 2);
            float v = acc[ms][r] + bb;
            if (flags & 1) v = fmaxf(v, 0.f);
            if (flags & 2) ((short*)Cout)[(size_t)row * N + col] = (short)f2bf(v);
            else           ((float*)Cout)[(size_t)row * N + col] = v;
        }
    }
}

// ---------------------------------------------------------------------------
// Fused QKV MFMA GEMM: A=xbf [4096,512]; grid.x = 24 n-tiles (which,h),
// grid.y = 32 m-tiles. Writes Q,K [bh][s][64] bf16; V transposed [bh][d][s].
// ---------------------------------------------------------------------------
__global__ __launch_bounds__(256, 2) void qkv_bf(
    const short* __restrict__ A,
    const short* __restrict__ Wqt, const short* __restrict__ Wkt, const short* __restrict__ Wvt,
    const float* __restrict__ bq, const float* __restrict__ bk, const float* __restrict__ bv,
    short* __restrict__ Oq, short* __restrict__ Ok, short* __restrict__ Ov)
{
    __shared__ short As[128 * LDT];
    __shared__ short Bs[64 * LDT];
    const int tid = threadIdx.x;
    const int wave = tid >> 6, lane = tid & 63;
    const int l31 = lane & 31, hi = lane >> 5;
    const int wm = wave >> 1, wn = wave & 1;
    const int m0 = blockIdx.y * 128;
    const int nt = blockIdx.x;
    const int which = nt >> 3, h = nt & 7;

    const short* Bt = ((which == 0) ? Wqt : (which == 1) ? Wkt : Wvt) + (size_t)h * 64 * 512;
    const float* bias = ((which == 0) ? bq : (which == 1) ? bk : bv) + h * 64;
    short* Out = (which == 0) ? Oq : (which == 1) ? Ok : Ov;

    f32x16 acc[2];
#pragma unroll
    for (int ms = 0; ms < 2; ++ms)
#pragma unroll
        for (int r = 0; r < 16; ++r) acc[ms][r] = 0.f;

    const int sr = tid >> 3;
    const int sc = (tid & 7) * 8;

    for (int k0 = 0; k0 < 512; k0 += 64) {
        __syncthreads();
#pragma unroll
        for (int p = 0; p < 4; ++p)
            *(short8*)&As[(p * 32 + sr) * LDT + sc] =
                *(const short8*)&A[(size_t)(m0 + p * 32 + sr) * 512 + k0 + sc];
#pragma unroll
        for (int p = 0; p < 2; ++p)
            *(short8*)&Bs[(p * 32 + sr) * LDT + sc] =
                *(const short8*)&Bt[(size_t)(p * 32 + sr) * 512 + k0 + sc];
        __syncthreads();

        short8 af[2][4], bfm[4];
#pragma unroll
        for (int ms = 0; ms < 2; ++ms)
#pragma unroll
            for (int ks = 0; ks < 4; ++ks)
                af[ms][ks] = *(const short8*)&As[(wm * 64 + ms * 32 + l31) * LDT + ks * 16 + hi * 8];
#pragma unroll
        for (int ks = 0; ks < 4; ++ks)
            bfm[ks] = *(const short8*)&Bs[(wn * 32 + l31) * LDT + ks * 16 + hi * 8];
#pragma unroll
        for (int ms = 0; ms < 2; ++ms)
#pragma unroll
            for (int ks = 0; ks < 4; ++ks)
                acc[ms] = __builtin_amdgcn_mfma_f32_32x32x16_bf16(af[ms][ks], bfm[ks], acc[ms], 0, 0, 0);
    }

    const int a = wn * 32 + l31;
    const float bb = bias[a];
    const int b = m0 >> 11;
    const int sb = (m0 & (SLEN - 1)) + wm * 64;
    const int bh = b * HHEADS + h;

    if (which < 2) {
        short* Ob = Out + (size_t)bh * SLEN * 64;
#pragma unroll
        for (int ms = 0; ms < 2; ++ms)
#pragma unroll
            for (int r = 0; r < 16; ++r) {
                int s = sb + ms * 32 + (r & 3) + 8 * (r >> 2) + 4 * hi;
                Ob[(size_t)s * 64 + a] = (short)f2bf(acc[ms][r] + bb);
            }
    } else {
        short* Ob = Out + ((size_t)bh * 64 + a) * SLEN;
#pragma unroll
        for (int ms = 0; ms < 2; ++ms)
#pragma unroll
            for (int g = 0; g < 4; ++g) {
                int s = sb + ms * 32 + 8 * g + 4 * hi;
                ushort4 w;
                w.x = f2bf(acc[ms][4 * g + 0] + bb);
                w.y = f2bf(acc[ms][4 * g + 1] + bb);
                w.z = f2bf(acc[ms][4 * g + 2] + bb);
                w.w = f2bf(acc[ms][4 * g + 3] + bb);
                *(ushort4*)&Ob[s] = w;
            }
    }
}

// ---------------------------------------------------------------------------
// MFMA flash attention, no-max softmax, key-split=2.
// grid (qt=8, bh=16, sp=2), 256 threads = 4 waves; wave owns 64 q-rows.
// ---------------------------------------------------------------------------
#define EXPC 0.1803368801111244f   // 0.125 * log2(e)

__global__ __launch_bounds__(256, 2) void attn_mfma(
    const short* __restrict__ Qb, const short* __restrict__ Kb,
    const short* __restrict__ Vtb, short* __restrict__ Op,
    float* __restrict__ lp)
{
    __shared__ short Ks[64 * 72];
    __shared__ short Vs[64 * 72];

    const int tid = threadIdx.x;
    const int wid = tid >> 6;
    const int lane = tid & 63;
    const int l31 = lane & 31;
    const int hi = lane >> 5;

    const int qt = blockIdx.x;
    const int bh = blockIdx.y;
    const int sp = blockIdx.z;

    const short* Qg = Qb + (size_t)bh * SLEN * 64;
    const short* Kg = Kb + (size_t)bh * SLEN * 64;
    const short* Vg = Vtb + (size_t)bh * 64 * SLEN;

    const int q0 = qt * 256 + wid * 64;

    short8 qf[2][4];
#pragma unroll
    for (int nt = 0; nt < 2; ++nt)
#pragma unroll
        for (int ks = 0; ks < 4; ++ks)
            qf[nt][ks] = *(const short8*)&Qg[(size_t)(q0 + nt * 32 + l31) * 64 + ks * 16 + hi * 8];

    f32x16 oacc[2][2];
#pragma unroll
    for (int nt = 0; nt < 2; ++nt)
#pragma unroll
        for (int dt = 0; dt < 2; ++dt)
#pragma unroll
            for (int r = 0; r < 16; ++r) oacc[nt][dt][r] = 0.f;
    float lsum[2] = {0.f, 0.f};

    const int srow = tid >> 2;
    const int sch = (tid & 3) * 16;

    for (int kt = 0; kt < 16; ++kt) {
        const int k0 = sp * (SLEN / SPLIT) + kt * 64;
        __syncthreads();
        *(short8*)&Ks[srow * 72 + sch]     = *(const short8*)&Kg[(size_t)(k0 + srow) * 64 + sch];
        *(short8*)&Ks[srow * 72 + sch + 8] = *(const short8*)&Kg[(size_t)(k0 + srow) * 64 + sch + 8];
        *(short8*)&Vs[srow * 72 + sch]     = *(const short8*)&Vg[(size_t)srow * SLEN + k0 + sch];
        *(short8*)&Vs[srow * 72 + sch + 8] = *(const short8*)&Vg[(size_t)srow * SLEN + k0 + sch + 8];
        __syncthreads();

        short8 kf[2][4], vf[2][4];
#pragma unroll
        for (int mt = 0; mt < 2; ++mt)
#pragma unroll
            for (int ks = 0; ks < 4; ++ks)
                kf[mt][ks] = *(const short8*)&Ks[(mt * 32 + l31) * 72 + ks * 16 + hi * 8];
#pragma unroll
        for (int dt = 0; dt < 2; ++dt)
#pragma unroll
            for (int p = 0; p < 4; ++p)
                vf[dt][p] = *(const short8*)&Vs[(dt * 32 + l31) * 72 + p * 16 + hi * 8];

#pragma unroll
        for (int nt = 0; nt < 2; ++nt) {
            f32x16 sacc[2];
#pragma unroll
            for (int mt = 0; mt < 2; ++mt) {
                f32x16 s;
#pragma unroll
                for (int r = 0; r < 16; ++r) s[r] = 0.f;
#pragma unroll
                for (int ks = 0; ks < 4; ++ks)
                    s = __builtin_amdgcn_mfma_f32_32x32x16_bf16(kf[mt][ks], qf[nt][ks], s, 0, 0, 0);
                sacc[mt] = s;
            }

            int2 pk[2][4], sh[2][4];
#pragma unroll
            for (int mt = 0; mt < 2; ++mt) {
#pragma unroll
                for (int g = 0; g < 4; ++g) {
                    float p0 = exp2f(sacc[mt][4 * g + 0] * EXPC);
                    float p1 = exp2f(sacc[mt][4 * g + 1] * EXPC);
                    float p2 = exp2f(sacc[mt][4 * g + 2] * EXPC);
                    float p3 = exp2f(sacc[mt][4 * g + 3] * EXPC);
                    lsum[nt] += (p0 + p1) + (p2 + p3);
                    pk[mt][g].x = f2bf_pk(p0, p1);
                    pk[mt][g].y = f2bf_pk(p2, p3);
                    sh[mt][g].x = __shfl_xor(pk[mt][g].x, 32);
                    sh[mt][g].y = __shfl_xor(pk[mt][g].y, 32);
                }
            }

#pragma unroll
            for (int p = 0; p < 4; ++p) {
                const int mt = p >> 1, h2 = p & 1;
                const int ga = 2 * h2, gb = 2 * h2 + 1;
                union { int4 i; short8 s; } u;
                u.i.x = hi ? sh[mt][gb].x : pk[mt][ga].x;
                u.i.y = hi ? sh[mt][gb].y : pk[mt][ga].y;
                u.i.z = hi ? pk[mt][gb].x : sh[mt][ga].x;
                u.i.w = hi ? pk[mt][gb].y : sh[mt][ga].y;
#pragma unroll
                for (int dt = 0; dt < 2; ++dt)
                    oacc[nt][dt] = __builtin_amdgcn_mfma_f32_32x32x16_bf16(u.s, vf[dt][p], oacc[nt][dt], 0, 0, 0);
            }
        }
    }

#pragma unroll
    for (int nt = 0; nt < 2; ++nt) {
        float lt = lsum[nt] + __shfl_xor(lsum[nt], 32);
        if (hi == 0)
            lp[((size_t)(sp * 16 + bh)) * SLEN + q0 + nt * 32 + l31] = lt;
#pragma unroll
        for (int dt = 0; dt < 2; ++dt) {
#pragma unroll
            for (int r = 0; r < 16; ++r) {
                int qrow = (r & 3) + 8 * (r >> 2) + 4 * hi;
                size_t addr = (((size_t)(sp * 16 + bh)) * SLEN + (q0 + nt * 32 + qrow)) * 64 + dt * 32 + l31;
                Op[addr] = (short)f2bf(oacc[nt][dt][r]);
            }
        }
    }
}

// ---------------------------------------------------------------------------
// Merge key-split partials -> hc bf16 [b,s, h*64+d]
// ---------------------------------------------------------------------------
__global__ __launch_bounds__(256) void merge_k(
    const short* __restrict__ Op, const float* __restrict__ lp,
    short* __restrict__ hc)
{
    const int g = blockIdx.x * 256 + threadIdx.x;
    const int d = g & 63;
    const int s = (g >> 6) & (SLEN - 1);
    const int bh = g >> 17;

    float o = 0.f, ls = 0.f;
#pragma unroll
    for (int sp = 0; sp < SPLIT; ++sp) {
        o += bf2f(Op[(((size_t)(sp * 16 + bh)) * SLEN + s) * 64 + d]);
        ls += lp[((size_t)(sp * 16 + bh)) * SLEN + s];
    }
    const int b = bh >> 3, h = bh & 7;
    hc[((size_t)(b * SLEN + s)) * DDIM + h * 64 + d] = (short)f2bf(o / ls);
}

// ---------------------------------------------------------------------------
// AddNorm on bf16 stream: xbf = LN(xbf + y) * g + b ; y fp32.
// One wave per token (lane owns 8 elems), 4 tokens/block.
// ---------------------------------------------------------------------------
__global__ __launch_bounds__(256) void addnorm_bf(
    short* __restrict__ X, const float* __restrict__ Y,
    const float* __restrict__ g, const float* __restrict__ beta)
{
    const int lane = threadIdx.x & 63;
    const int t = blockIdx.x * 4 + (threadIdx.x >> 6);
    short* xr = X + (size_t)t * DDIM;
    const float* yr = Y + (size_t)t * DDIM;
    const int c0 = lane * 8;

    short8 x8 = *(const short8*)&xr[c0];
    float4 y0 = *(const float4*)&yr[c0];
    float4 y1 = *(const float4*)&yr[c0 + 4];
    float v[8];
    v[0] = bf2f(x8[0]) + y0.x; v[1] = bf2f(x8[1]) + y0.y;
    v[2] = bf2f(x8[2]) + y0.z; v[3] = bf2f(x8[3]) + y0.w;
    v[4] = bf2f(x8[4]) + y1.x; v[5] = bf2f(x8[5]) + y1.y;
    v[6] = bf2f(x8[6]) + y1.z; v[7] = bf2f(x8[7]) + y1.w;

    float s1 = 0.f, s2 = 0.f;
#pragma unroll
    for (int j = 0; j < 8; ++j) { s1 += v[j]; s2 += v[j] * v[j]; }
#pragma unroll
    for (int off = 1; off < 64; off <<= 1) {
        s1 += __shfl_xor(s1, off);
        s2 += __shfl_xor(s2, off);
    }
    float mean = s1 * (1.0f / DDIM);
    float var = s2 * (1.0f / DDIM) - mean * mean;
    float rstd = rsqrtf(var + 1e-5f);

    float4 ga = *(const float4*)&g[c0];
    float4 gb = *(const float4*)&g[c0 + 4];
    float4 ba = *(const float4*)&beta[c0];
    float4 bb = *(const float4*)&beta[c0 + 4];
    float gg[8] = {ga.x, ga.y, ga.z, ga.w, gb.x, gb.y, gb.z, gb.w};
    float bt[8] = {ba.x, ba.y, ba.z, ba.w, bb.x, bb.y, bb.z, bb.w};

    short8 o8;
#pragma unroll
    for (int j = 0; j < 8; ++j)
        o8[j] = (short)f2bf((v[j] - mean) * rstd * gg[j] + bt[j]);
    *(short8*)&xr[c0] = o8;
}

// ---------------------------------------------------------------------------
// Workspace (MiB), overlays lifetime-checked, total 35.25 MiB:
//   [ 0, 4)  xbf (bf16, alive always)
//   [ 4, 8)  Qbuf  | hcbf overlays (Q dead after attn; hc dead after Wo)
//   [ 8,12)  Kbuf
//   [12,16)  Vtbuf
//   [16,24)  Opart (attn->merge) | y fp32 (Wo->an1, ffn2->an2)
//   [24,28)  hidbf (ffn1->ffn2)
//   [28,28.25) lpart
//   [29,35.25) weights bf16 (Wqt,Wkt,Wvt,Wot,W1t,W2t @1MiB each; Wpt 0.25)
// ---------------------------------------------------------------------------
extern "C" void kernel_launch(void* const* d_in, const int* in_sizes, int n_in,
                              void* d_out, int out_size, void* d_ws, size_t ws_size,
                              hipStream_t stream)
{
    (void)in_sizes; (void)n_in; (void)out_size; (void)ws_size;
    const float* x   = (const float*)d_in[0];
    const float* Wq  = (const float*)d_in[1];
    const float* bq  = (const float*)d_in[2];
    const float* Wk  = (const float*)d_in[3];
    const float* bk  = (const float*)d_in[4];
    const float* Wv  = (const float*)d_in[5];
    const float* bv  = (const float*)d_in[6];
    const float* Wo  = (const float*)d_in[7];
    const float* bo  = (const float*)d_in[8];
    const float* g1  = (const float*)d_in[9];
    const float* be1 = (const float*)d_in[10];
    const float* W1  = (const float*)d_in[11];
    const float* b1  = (const float*)d_in[12];
    const float* W2  = (const float*)d_in[13];
    const float* b2  = (const float*)d_in[14];
    const float* g2  = (const float*)d_in[15];
    const float* be2 = (const float*)d_in[16];
    const float* Wp  = (const float*)d_in[17];
    const float* bp  = (const float*)d_in[18];

    char* wsb = (char*)d_ws;
    const size_t MB = 1024 * 1024;
    short* xbf   = (short*)(wsb + 0);
    short* Qbuf  = (short*)(wsb + 4 * MB);
    short* Kbuf  = (short*)(wsb + 8 * MB);
    short* Vtbuf = (short*)(wsb + 12 * MB);
    short* Opart = (short*)(wsb + 16 * MB);
    float* y     = (float*)(wsb + 16 * MB);   // overlays Opart (disjoint lifetime)
    short* hidbf = (short*)(wsb + 24 * MB);
    float* lpart = (float*)(wsb + 28 * MB);
    short* hcbf  = Qbuf;                       // overlays Qbuf
    short* Wqt   = (short*)(wsb + 29 * MB);
    short* Wkt   = (short*)(wsb + 30 * MB);
    short* Wvt   = (short*)(wsb + 31 * MB);
    short* Wot   = (short*)(wsb + 32 * MB);
    short* W1t   = (short*)(wsb + 33 * MB);
    short* W2t   = (short*)(wsb + 34 * MB);
    short* Wpt   = (short*)(wsb + 35 * MB);

    prep_k<<<20992, 256, 0, stream>>>(Wq, Wk, Wv, Wo, W1, W2, Wp, x,
                                      Wqt, Wkt, Wvt, Wot, W1t, W2t, Wpt, xbf);

    for (int i = 0; i < 2; ++i) {
        const size_t wOffQ = (size_t)i * 262144;   // 8*64*512
        const size_t wOffS = (size_t)i * 262144;   // 512*512
        qkv_bf<<<dim3(24, 32), 256, 0, stream>>>(
            xbf, Wqt + wOffQ, Wkt + wOffQ, Wvt + wOffQ,
            bq + i * 512, bk + i * 512, bv + i * 512,
            Qbuf, Kbuf, Vtbuf);
        attn_mfma<<<dim3(8, 16, SPLIT), 256, 0, stream>>>(Qbuf, Kbuf, Vtbuf, Opart, lpart);
        merge_k<<<8192, 256, 0, stream>>>(Opart, lpart, hcbf);
        gemm_bf<<<dim3(8, 32), 256, 0, stream>>>(
            hcbf, Wot + wOffS, bo + i * 512, y, MDIM, DDIM, DDIM, 0);
        addnorm_bf<<<1024, 256, 0, stream>>>(xbf, y, g1 + i * 512, be1 + i * 512);
        gemm_bf<<<dim3(8, 32), 256, 0, stream>>>(
            xbf, W1t + wOffS, b1 + i * 512, hidbf, MDIM, DDIM, DDIM, 3);
        gemm_bf<<<dim3(8, 32), 256, 0, stream>>>(
            hidbf, W2t + wOffS, b2 + i * 512, y, MDIM, DDIM, DDIM, 0);
        addnorm_bf<<<1024, 256, 0, stream>>>(xbf, y, g2 + i * 512, be2 + i * 512);
    }
    gemm_bf<<<dim3(4, 32), 256, 0, stream>>>(
        xbf, Wpt, bp, (float*)d_out, MDIM, TDIM, DDIM, 0);
}

// Round 6
// 294.937 us; speedup vs baseline: 4.3269x; 1.4114x over previous
//
#include <hip/hip_runtime.h>
#include <hip/hip_bf16.h>

#define MDIM 4096      // B*S tokens
#define DDIM 512
#define ADIM 64
#define HHEADS 8
#define SLEN 2048
#define TDIM 256
#define SPLIT 4

typedef __attribute__((ext_vector_type(8))) short short8;
typedef __attribute__((ext_vector_type(16))) float f32x16;

__device__ __forceinline__ unsigned short f2bf(float f) {
    union { __hip_bfloat16 h; unsigned short u; } c;
    c.h = __float2bfloat16(f);
    return c.u;
}
__device__ __forceinline__ float bf2f(short s) {
    return __uint_as_float((unsigned)(unsigned short)s << 16);
}

// ---------------------------------------------------------------------------
// prep: weights fp32 -> bf16 transposed; x -> bf16. Coalesced READS,
// scattered 2B stores (stores don't stall; L2 absorbs the RMW).
//   Wq/Wk/Wv [L*H, D, A] -> [L*H, A, D] ; Wo/W1/W2 [L,K,N] -> [L,N,K] ;
//   Wp [K,T] -> [T,K] ; x fp32 -> bf16
// ---------------------------------------------------------------------------
#define N1 524288
#define N2 524288
#define NP 131072
__global__ __launch_bounds__(256) void prep_k(
    const float* __restrict__ Wq, const float* __restrict__ Wk, const float* __restrict__ Wv,
    const float* __restrict__ Wo, const float* __restrict__ W1, const float* __restrict__ W2,
    const float* __restrict__ Wp, const float* __restrict__ x,
    short* __restrict__ Wqt, short* __restrict__ Wkt, short* __restrict__ Wvt,
    short* __restrict__ Wot, short* __restrict__ W1t, short* __restrict__ W2t,
    short* __restrict__ Wpt, short* __restrict__ xbf)
{
    long idx = (long)blockIdx.x * 256 + threadIdx.x;
    if (idx < 3L * N1) {
        int t = (int)(idx / N1);
        int r = (int)(idx % N1);
        int a = r & 63, k = (r >> 6) & 511, hh = r >> 15;
        const float* src = (t == 0) ? Wq : (t == 1) ? Wk : Wv;
        short* dst = (t == 0) ? Wqt : (t == 1) ? Wkt : Wvt;
        dst[((size_t)hh << 15) + (a << 9) + k] = (short)f2bf(src[r]);
        return;
    }
    idx -= 3L * N1;
    if (idx < 3L * N2) {
        int t = (int)(idx / N2);
        int r = (int)(idx % N2);
        int n = r & 511, k = (r >> 9) & 511, i = r >> 18;
        const float* src = (t == 0) ? Wo : (t == 1) ? W1 : W2;
        short* dst = (t == 0) ? Wot : (t == 1) ? W1t : W2t;
        dst[((size_t)i << 18) + (n << 9) + k] = (short)f2bf(src[r]);
        return;
    }
    idx -= 3L * N2;
    if (idx < NP) {
        int r = (int)idx;
        int n = r & 255, k = r >> 8;
        Wpt[n * 512 + k] = (short)f2bf(Wp[r]);
        return;
    }
    idx -= NP;
    xbf[idx] = (short)f2bf(x[idx]);
}

// ---------------------------------------------------------------------------
// bf16 MFMA GEMM: C[M,N] = A[M,K] @ B + bias. B TRANSPOSED: Bt[n][k].
// Tile 64m x 64n, BK=64, 4 waves (2m x 2n), wave = 32x32.
// flags: 1=relu, 2=bf16 out.
// ---------------------------------------------------------------------------
#define LDT 66
__global__ __launch_bounds__(256, 2) void gemm_bf(
    const short* __restrict__ A, const short* __restrict__ Bt,
    const float* __restrict__ bias, void* __restrict__ Cout,
    int M, int N, int K, int flags)
{
    __shared__ short As[64 * LDT];
    __shared__ short Bs[64 * LDT];
    const int tid = threadIdx.x;
    const int wave = tid >> 6, lane = tid & 63;
    const int l31 = lane & 31, hi = lane >> 5;
    const int wm = wave >> 1, wn = wave & 1;
    const int m0 = blockIdx.y * 64, n0 = blockIdx.x * 64;

    f32x16 acc;
#pragma unroll
    for (int r = 0; r < 16; ++r) acc[r] = 0.f;

    const int sr = tid >> 2;          // 0..63
    const int sc = (tid & 3) * 16;    // short chunk

    for (int k0 = 0; k0 < K; k0 += 64) {
        __syncthreads();
        *(short8*)&As[sr * LDT + sc]     = *(const short8*)&A[(size_t)(m0 + sr) * K + k0 + sc];
        *(short8*)&As[sr * LDT + sc + 8] = *(const short8*)&A[(size_t)(m0 + sr) * K + k0 + sc + 8];
        *(short8*)&Bs[sr * LDT + sc]     = *(const short8*)&Bt[(size_t)(n0 + sr) * K + k0 + sc];
        *(short8*)&Bs[sr * LDT + sc + 8] = *(const short8*)&Bt[(size_t)(n0 + sr) * K + k0 + sc + 8];
        __syncthreads();

        short8 af[4], bfm[4];
#pragma unroll
        for (int ks = 0; ks < 4; ++ks) {
            af[ks]  = *(const short8*)&As[(wm * 32 + l31) * LDT + ks * 16 + hi * 8];
            bfm[ks] = *(const short8*)&Bs[(wn * 32 + l31) * LDT + ks * 16 + hi * 8];
        }
#pragma unroll
        for (int ks = 0; ks < 4; ++ks)
            acc = __builtin_amdgcn_mfma_f32_32x32x16_bf16(af[ks], bfm[ks], acc, 0, 0, 0);
    }

    const int col = n0 + wn * 32 + l31;
    const float bb = bias[col];
    const int rbase = m0 + wm * 32 + 4 * hi;
#pragma unroll
    for (int r = 0; r < 16; ++r) {
        int row = rbase + (r & 3) + 8 * (r >> 2);
        float v = acc[r] + bb;
        if (flags & 1) v = fmaxf(v, 0.f);
        if (flags & 2) ((short*)Cout)[(size_t)row * N + col] = (short)f2bf(v);
        else           ((float*)Cout)[(size_t)row * N + col] = v;
    }
}

// ---------------------------------------------------------------------------
// Fused QKV MFMA GEMM: A=xbf [4096,512]; grid (24 n-tiles, 32 m-tiles).
// Q pre-scaled by 0.125*log2(e); Q,K [bh][s][64] bf16; V transposed [bh][d][s].
// ---------------------------------------------------------------------------
#define EXPC 0.1803368801111244f   // 0.125 * log2(e)

__global__ __launch_bounds__(256, 2) void qkv_bf(
    const short* __restrict__ A,
    const short* __restrict__ Wqt, const short* __restrict__ Wkt, const short* __restrict__ Wvt,
    const float* __restrict__ bq, const float* __restrict__ bk, const float* __restrict__ bv,
    short* __restrict__ Oq, short* __restrict__ Ok, short* __restrict__ Ov)
{
    __shared__ short As[128 * LDT];
    __shared__ short Bs[64 * LDT];
    const int tid = threadIdx.x;
    const int wave = tid >> 6, lane = tid & 63;
    const int l31 = lane & 31, hi = lane >> 5;
    const int wm = wave >> 1, wn = wave & 1;
    const int m0 = blockIdx.y * 128;
    const int nt = blockIdx.x;
    const int which = nt >> 3, h = nt & 7;

    const short* Bt = ((which == 0) ? Wqt : (which == 1) ? Wkt : Wvt) + (size_t)h * 64 * 512;
    const float* bias = ((which == 0) ? bq : (which == 1) ? bk : bv) + h * 64;
    short* Out = (which == 0) ? Oq : (which == 1) ? Ok : Ov;

    f32x16 acc[2];
#pragma unroll
    for (int ms = 0; ms < 2; ++ms)
#pragma unroll
        for (int r = 0; r < 16; ++r) acc[ms][r] = 0.f;

    const int sr = tid >> 3;
    const int sc = (tid & 7) * 8;

    for (int k0 = 0; k0 < 512; k0 += 64) {
        __syncthreads();
#pragma unroll
        for (int p = 0; p < 4; ++p)
            *(short8*)&As[(p * 32 + sr) * LDT + sc] =
                *(const short8*)&A[(size_t)(m0 + p * 32 + sr) * 512 + k0 + sc];
#pragma unroll
        for (int p = 0; p < 2; ++p)
            *(short8*)&Bs[(p * 32 + sr) * LDT + sc] =
                *(const short8*)&Bt[(size_t)(p * 32 + sr) * 512 + k0 + sc];
        __syncthreads();

        short8 af[2][4], bfm[4];
#pragma unroll
        for (int ms = 0; ms < 2; ++ms)
#pragma unroll
            for (int ks = 0; ks < 4; ++ks)
                af[ms][ks] = *(const short8*)&As[(wm * 64 + ms * 32 + l31) * LDT + ks * 16 + hi * 8];
#pragma unroll
        for (int ks = 0; ks < 4; ++ks)
            bfm[ks] = *(const short8*)&Bs[(wn * 32 + l31) * LDT + ks * 16 + hi * 8];
#pragma unroll
        for (int ms = 0; ms < 2; ++ms)
#pragma unroll
            for (int ks = 0; ks < 4; ++ks)
                acc[ms] = __builtin_amdgcn_mfma_f32_32x32x16_bf16(af[ms][ks], bfm[ks], acc[ms], 0, 0, 0);
    }

    const int a = wn * 32 + l31;
    const float bb = bias[a];
    const int b = m0 >> 11;
    const int sb = (m0 & (SLEN - 1)) + wm * 64;
    const int bh = b * HHEADS + h;

    if (which == 0) {
        short* Ob = Out + (size_t)bh * SLEN * 64;
#pragma unroll
        for (int ms = 0; ms < 2; ++ms)
#pragma unroll
            for (int r = 0; r < 16; ++r) {
                int s = sb + ms * 32 + (r & 3) + 8 * (r >> 2) + 4 * hi;
                Ob[(size_t)s * 64 + a] = (short)f2bf((acc[ms][r] + bb) * EXPC);
            }
    } else if (which == 1) {
        short* Ob = Out + (size_t)bh * SLEN * 64;
#pragma unroll
        for (int ms = 0; ms < 2; ++ms)
#pragma unroll
            for (int r = 0; r < 16; ++r) {
                int s = sb + ms * 32 + (r & 3) + 8 * (r >> 2) + 4 * hi;
                Ob[(size_t)s * 64 + a] = (short)f2bf(acc[ms][r] + bb);
            }
    } else {
        short* Ob = Out + ((size_t)bh * 64 + a) * SLEN;
#pragma unroll
        for (int ms = 0; ms < 2; ++ms)
#pragma unroll
            for (int g = 0; g < 4; ++g) {
                int s = sb + ms * 32 + 8 * g + 4 * hi;
                ushort4 w;
                w.x = f2bf(acc[ms][4 * g + 0] + bb);
                w.y = f2bf(acc[ms][4 * g + 1] + bb);
                w.z = f2bf(acc[ms][4 * g + 2] + bb);
                w.w = f2bf(acc[ms][4 * g + 3] + bb);
                *(ushort4*)&Ob[s] = w;
            }
    }
}

// ---------------------------------------------------------------------------
// MFMA flash attention, no-max softmax (Q pre-scaled), key-split=4.
// grid (qt=8, bh=16, sp=4). l computed via ones-B MFMA; P packed by
// v_perm truncation; half-exchange via single pre-selected shfl_xor(32).
// ---------------------------------------------------------------------------
__global__ __launch_bounds__(256, 2) void attn_mfma(
    const short* __restrict__ Qb, const short* __restrict__ Kb,
    const short* __restrict__ Vtb, short* __restrict__ Op,
    float* __restrict__ lp)
{
    __shared__ short Ks[64 * 72];
    __shared__ short Vs[64 * 72];

    const int tid = threadIdx.x;
    const int wid = tid >> 6;
    const int lane = tid & 63;
    const int l31 = lane & 31;
    const int hi = lane >> 5;

    const int qt = blockIdx.x;
    const int bh = blockIdx.y;
    const int sp = blockIdx.z;

    const short* Qg = Qb + (size_t)bh * SLEN * 64;
    const short* Kg = Kb + (size_t)bh * SLEN * 64;
    const short* Vg = Vtb + (size_t)bh * 64 * SLEN;

    const int q0 = qt * 256 + wid * 64;

    short8 qf[2][4];
#pragma unroll
    for (int nt = 0; nt < 2; ++nt)
#pragma unroll
        for (int ks = 0; ks < 4; ++ks)
            qf[nt][ks] = *(const short8*)&Qg[(size_t)(q0 + nt * 32 + l31) * 64 + ks * 16 + hi * 8];

    f32x16 oacc[2][2], lacc[2];
#pragma unroll
    for (int nt = 0; nt < 2; ++nt) {
#pragma unroll
        for (int r = 0; r < 16; ++r) lacc[nt][r] = 0.f;
#pragma unroll
        for (int dt = 0; dt < 2; ++dt)
#pragma unroll
            for (int r = 0; r < 16; ++r) oacc[nt][dt][r] = 0.f;
    }

    short8 ones;
#pragma unroll
    for (int j = 0; j < 8; ++j) ones[j] = (short)0x3F80;   // bf16 1.0

    const int srow = tid >> 2;
    const int sch = (tid & 3) * 16;

    for (int kt = 0; kt < 8; ++kt) {
        const int k0 = sp * (SLEN / SPLIT) + kt * 64;
        __syncthreads();
        *(short8*)&Ks[srow * 72 + sch]     = *(const short8*)&Kg[(size_t)(k0 + srow) * 64 + sch];
        *(short8*)&Ks[srow * 72 + sch + 8] = *(const short8*)&Kg[(size_t)(k0 + srow) * 64 + sch + 8];
        *(short8*)&Vs[srow * 72 + sch]     = *(const short8*)&Vg[(size_t)srow * SLEN + k0 + sch];
        *(short8*)&Vs[srow * 72 + sch + 8] = *(const short8*)&Vg[(size_t)srow * SLEN + k0 + sch + 8];
        __syncthreads();

        short8 kf[2][4], vf[2][4];
#pragma unroll
        for (int mt = 0; mt < 2; ++mt)
#pragma unroll
            for (int ks = 0; ks < 4; ++ks)
                kf[mt][ks] = *(const short8*)&Ks[(mt * 32 + l31) * 72 + ks * 16 + hi * 8];
#pragma unroll
        for (int dt = 0; dt < 2; ++dt)
#pragma unroll
            for (int p = 0; p < 4; ++p)
                vf[dt][p] = *(const short8*)&Vs[(dt * 32 + l31) * 72 + p * 16 + hi * 8];

#pragma unroll
        for (int nt = 0; nt < 2; ++nt) {
            f32x16 sacc[2];
#pragma unroll
            for (int mt = 0; mt < 2; ++mt) {
                f32x16 s;
#pragma unroll
                for (int r = 0; r < 16; ++r) s[r] = 0.f;
#pragma unroll
                for (int ks = 0; ks < 4; ++ks)
                    s = __builtin_amdgcn_mfma_f32_32x32x16_bf16(kf[mt][ks], qf[nt][ks], s, 0, 0, 0);
                sacc[mt] = s;
            }

            // p = exp2(s) (scale folded into Q); pack pairs via v_perm truncation
            int2 pk[2][4];
#pragma unroll
            for (int mt = 0; mt < 2; ++mt)
#pragma unroll
                for (int g = 0; g < 4; ++g) {
                    unsigned a0 = __float_as_uint(__builtin_amdgcn_exp2f(sacc[mt][4 * g + 0]));
                    unsigned a1 = __float_as_uint(__builtin_amdgcn_exp2f(sacc[mt][4 * g + 1]));
                    unsigned a2 = __float_as_uint(__builtin_amdgcn_exp2f(sacc[mt][4 * g + 2]));
                    unsigned a3 = __float_as_uint(__builtin_amdgcn_exp2f(sacc[mt][4 * g + 3]));
                    pk[mt][g].x = (int)__builtin_amdgcn_perm(a1, a0, 0x07060302u);
                    pk[mt][g].y = (int)__builtin_amdgcn_perm(a3, a2, 0x07060302u);
                }

            // minimal cross-half exchange: partner needs pk[2h2 + (1-hi)]
            int2 xch[2][2];
#pragma unroll
            for (int mt = 0; mt < 2; ++mt)
#pragma unroll
                for (int h2 = 0; h2 < 2; ++h2) {
                    int2 v = hi ? pk[mt][2 * h2] : pk[mt][2 * h2 + 1];
                    xch[mt][h2].x = __shfl_xor(v.x, 32);
                    xch[mt][h2].y = __shfl_xor(v.y, 32);
                }

#pragma unroll
            for (int p = 0; p < 4; ++p) {
                const int mt = p >> 1, h2 = p & 1;
                const int ga = 2 * h2, gb = 2 * h2 + 1;
                const int2 X = xch[mt][h2];
                union { int4 i; short8 s; } u;
                u.i.x = hi ? X.x : pk[mt][ga].x;
                u.i.y = hi ? X.y : pk[mt][ga].y;
                u.i.z = hi ? pk[mt][gb].x : X.x;
                u.i.w = hi ? pk[mt][gb].y : X.y;
                lacc[nt] = __builtin_amdgcn_mfma_f32_32x32x16_bf16(u.s, ones, lacc[nt], 0, 0, 0);
#pragma unroll
                for (int dt = 0; dt < 2; ++dt)
                    oacc[nt][dt] = __builtin_amdgcn_mfma_f32_32x32x16_bf16(u.s, vf[dt][p], oacc[nt][dt], 0, 0, 0);
            }
        }
    }

#pragma unroll
    for (int nt = 0; nt < 2; ++nt) {
        if (l31 == 0) {
#pragma unroll
            for (int r = 0; r < 16; ++r) {
                int qrow = (r & 3) + 8 * (r >> 2) + 4 * hi;
                lp[((size_t)(sp * 16 + bh)) * SLEN + q0 + nt * 32 + qrow] = lacc[nt][r];
            }
        }
#pragma unroll
        for (int dt = 0; dt < 2; ++dt) {
#pragma unroll
            for (int r = 0; r < 16; ++r) {
                int qrow = (r & 3) + 8 * (r >> 2) + 4 * hi;
                size_t addr = (((size_t)(sp * 16 + bh)) * SLEN + (q0 + nt * 32 + qrow)) * 64 + dt * 32 + l31;
                Op[addr] = (short)f2bf(oacc[nt][dt][r]);
            }
        }
    }
}

// ---------------------------------------------------------------------------
// Merge key-split partials -> hc bf16 [b,s, h*64+d]; 4 d-elems per thread
// ---------------------------------------------------------------------------
__global__ __launch_bounds__(256) void merge_k(
    const short* __restrict__ Op, const float* __restrict__ lp,
    short* __restrict__ hc)
{
    const int g = blockIdx.x * 256 + threadIdx.x;   // 512K threads
    const int d4 = g & 15;
    const int s = (g >> 4) & (SLEN - 1);
    const int bh = g >> 15;

    float o[4] = {0.f, 0.f, 0.f, 0.f};
    float ls = 0.f;
#pragma unroll
    for (int sp = 0; sp < SPLIT; ++sp) {
        const size_t base = (((size_t)(sp * 16 + bh)) * SLEN + s);
        ushort4 u4 = *(const ushort4*)&Op[base * 64 + d4 * 4];
        o[0] += bf2f((short)u4.x); o[1] += bf2f((short)u4.y);
        o[2] += bf2f((short)u4.z); o[3] += bf2f((short)u4.w);
        ls += lp[base];
    }
    const int b = bh >> 3, h = bh & 7;
    const float inv = 1.f / ls;
    ushort4 w;
    w.x = f2bf(o[0] * inv); w.y = f2bf(o[1] * inv);
    w.z = f2bf(o[2] * inv); w.w = f2bf(o[3] * inv);
    *(ushort4*)&hc[((size_t)(b * SLEN + s)) * DDIM + h * 64 + d4 * 4] = w;
}

// ---------------------------------------------------------------------------
// AddNorm on bf16 stream: xbf = LN(xbf + y) * g + b ; y fp32.
// ---------------------------------------------------------------------------
__global__ __launch_bounds__(256) void addnorm_bf(
    short* __restrict__ X, const float* __restrict__ Y,
    const float* __restrict__ g, const float* __restrict__ beta)
{
    const int lane = threadIdx.x & 63;
    const int t = blockIdx.x * 4 + (threadIdx.x >> 6);
    short* xr = X + (size_t)t * DDIM;
    const float* yr = Y + (size_t)t * DDIM;
    const int c0 = lane * 8;

    short8 x8 = *(const short8*)&xr[c0];
    float4 y0 = *(const float4*)&yr[c0];
    float4 y1 = *(const float4*)&yr[c0 + 4];
    float v[8];
    v[0] = bf2f(x8[0]) + y0.x; v[1] = bf2f(x8[1]) + y0.y;
    v[2] = bf2f(x8[2]) + y0.z; v[3] = bf2f(x8[3]) + y0.w;
    v[4] = bf2f(x8[4]) + y1.x; v[5] = bf2f(x8[5]) + y1.y;
    v[6] = bf2f(x8[6]) + y1.z; v[7] = bf2f(x8[7]) + y1.w;

    float s1 = 0.f, s2 = 0.f;
#pragma unroll
    for (int j = 0; j < 8; ++j) { s1 += v[j]; s2 += v[j] * v[j]; }
#pragma unroll
    for (int off = 1; off < 64; off <<= 1) {
        s1 += __shfl_xor(s1, off);
        s2 += __shfl_xor(s2, off);
    }
    float mean = s1 * (1.0f / DDIM);
    float var = s2 * (1.0f / DDIM) - mean * mean;
    float rstd = rsqrtf(var + 1e-5f);

    float4 ga = *(const float4*)&g[c0];
    float4 gb = *(const float4*)&g[c0 + 4];
    float4 ba = *(const float4*)&beta[c0];
    float4 bb = *(const float4*)&beta[c0 + 4];
    float gg[8] = {ga.x, ga.y, ga.z, ga.w, gb.x, gb.y, gb.z, gb.w};
    float bt[8] = {ba.x, ba.y, ba.z, ba.w, bb.x, bb.y, bb.z, bb.w};

    short8 o8;
#pragma unroll
    for (int j = 0; j < 8; ++j)
        o8[j] = (short)f2bf((v[j] - mean) * rstd * gg[j] + bt[j]);
    *(short8*)&xr[c0] = o8;
}

// ---------------------------------------------------------------------------
// Workspace (MiB), overlays lifetime-checked, total 39.25 MiB (< proven 40):
//   [ 0, 4)  xbf            (alive whole run)
//   [ 4, 8)  Qbuf | hcbf    (Q dead after attn; hc dead after Wo)
//   [ 8,12)  Kbuf
//   [12,16)  Vtbuf
//   [16,32)  Opart (attn->merge) | y fp32 [16,24) | hidbf [24,28)
//   [32,32.5) lpart
//   [33,39.25) weights bf16
// ---------------------------------------------------------------------------
extern "C" void kernel_launch(void* const* d_in, const int* in_sizes, int n_in,
                              void* d_out, int out_size, void* d_ws, size_t ws_size,
                              hipStream_t stream)
{
    (void)in_sizes; (void)n_in; (void)out_size; (void)ws_size;
    const float* x   = (const float*)d_in[0];
    const float* Wq  = (const float*)d_in[1];
    const float* bq  = (const float*)d_in[2];
    const float* Wk  = (const float*)d_in[3];
    const float* bk  = (const float*)d_in[4];
    const float* Wv  = (const float*)d_in[5];
    const float* bv  = (const float*)d_in[6];
    const float* Wo  = (const float*)d_in[7];
    const float* bo  = (const float*)d_in[8];
    const float* g1  = (const float*)d_in[9];
    const float* be1 = (const float*)d_in[10];
    const float* W1  = (const float*)d_in[11];
    const float* b1  = (const float*)d_in[12];
    const float* W2  = (const float*)d_in[13];
    const float* b2  = (const float*)d_in[14];
    const float* g2  = (const float*)d_in[15];
    const float* be2 = (const float*)d_in[16];
    const float* Wp  = (const float*)d_in[17];
    const float* bp  = (const float*)d_in[18];

    char* wsb = (char*)d_ws;
    const size_t MB = 1024 * 1024;
    short* xbf   = (short*)(wsb + 0);
    short* Qbuf  = (short*)(wsb + 4 * MB);
    short* Kbuf  = (short*)(wsb + 8 * MB);
    short* Vtbuf = (short*)(wsb + 12 * MB);
    short* Opart = (short*)(wsb + 16 * MB);
    float* y     = (float*)(wsb + 16 * MB);   // overlay (disjoint lifetime)
    short* hidbf = (short*)(wsb + 24 * MB);   // overlay (disjoint lifetime)
    float* lpart = (float*)(wsb + 32 * MB);
    short* hcbf  = Qbuf;                       // overlay
    short* Wqt   = (short*)(wsb + 33 * MB);
    short* Wkt   = (short*)(wsb + 34 * MB);
    short* Wvt   = (short*)(wsb + 35 * MB);
    short* Wot   = (short*)(wsb + 36 * MB);
    short* W1t   = (short*)(wsb + 37 * MB);
    short* W2t   = (short*)(wsb + 38 * MB);
    short* Wpt   = (short*)(wsb + 39 * MB);

    prep_k<<<20992, 256, 0, stream>>>(Wq, Wk, Wv, Wo, W1, W2, Wp, x,
                                      Wqt, Wkt, Wvt, Wot, W1t, W2t, Wpt, xbf);

    for (int i = 0; i < 2; ++i) {
        const size_t wOffQ = (size_t)i * 262144;
        const size_t wOffS = (size_t)i * 262144;
        qkv_bf<<<dim3(24, 32), 256, 0, stream>>>(
            xbf, Wqt + wOffQ, Wkt + wOffQ, Wvt + wOffQ,
            bq + i * 512, bk + i * 512, bv + i * 512,
            Qbuf, Kbuf, Vtbuf);
        attn_mfma<<<dim3(8, 16, SPLIT), 256, 0, stream>>>(Qbuf, Kbuf, Vtbuf, Opart, lpart);
        merge_k<<<2048, 256, 0, stream>>>(Opart, lpart, hcbf);
        gemm_bf<<<dim3(8, 64), 256, 0, stream>>>(
            hcbf, Wot + wOffS, bo + i * 512, y, MDIM, DDIM, DDIM, 0);
        addnorm_bf<<<1024, 256, 0, stream>>>(xbf, y, g1 + i * 512, be1 + i * 512);
        gemm_bf<<<dim3(8, 64), 256, 0, stream>>>(
            xbf, W1t + wOffS, b1 + i * 512, hidbf, MDIM, DDIM, DDIM, 3);
        gemm_bf<<<dim3(8, 64), 256, 0, stream>>>(
            hidbf, W2t + wOffS, b2 + i * 512, y, MDIM, DDIM, DDIM, 0);
        addnorm_bf<<<1024, 256, 0, stream>>>(xbf, y, g2 + i * 512, be2 + i * 512);
    }
    gemm_bf<<<dim3(4, 64), 256, 0, stream>>>(
        xbf, Wpt, bp, (float*)d_out, MDIM, TDIM, DDIM, 0);
}